// Round 6
// baseline (206.291 us; speedup 1.0000x reference)
//
#include <hip/hip_runtime.h>
#include <math.h>

// Problem constants (reference: N=16384, D=128, T=0.07)
#define NROWS 16384
#define DDIM  128
constexpr float TEMP = 0.07f;
// Pre-scale trick: x *= sqrt(log2(e)/T) so MFMA emits acc = S*<xi,xj> and
// row_lse = ln(sum exp2(acc)). The DIAGONAL (sim_ii = 1 exactly, rows unit
// norm) is masked out of the MFMA path and added analytically in finalize:
// rowsum_i = offdiag_fp8_sum_i + 2^S. Off-diag is only ~2.3% of rowsum, so
// fp8 e4m3 error there is damped ~44x -> absmax ~0.006 vs threshold 0.286.
constexpr float S_EXP = 1.44269504088896f / TEMP;  // 20.6099291

typedef __attribute__((ext_vector_type(4))) float f32x4;

// Convert + pre-scale to fp8 e4m3 (OCP, RNE via v_cvt_pk_fp8_f32); zero accum/cnt.
__global__ void convert_k(const float* __restrict__ x, unsigned char* __restrict__ xb,
                          float* __restrict__ accum, int* __restrict__ cnt) {
  const float R = 4.53981419f;  // sqrt(S_EXP); |x*R| <= ~1.3, well inside e4m3 range
  int i = (blockIdx.x * blockDim.x + threadIdx.x) * 4;
  float4 v = *(const float4*)(x + i);
  int p = __builtin_amdgcn_cvt_pk_fp8_f32(v.x * R, v.y * R, 0, false);
  p = __builtin_amdgcn_cvt_pk_fp8_f32(v.z * R, v.w * R, p, true);
  *(int*)(xb + i) = p;
  if (blockIdx.x == 0 && threadIdx.x == 0) { *accum = 0.f; *cnt = 0; }
}

// Triangular Gram in fp8 — ROUND-6: NO LDS STAGING. xb is 2 MB, fully
// L2-resident per XCD (4 MB), so the panel-staging apparatus (gload_lds,
// 32 KB LDS, swizzle, 16 ds_read/wave/tile, 4.26M bank conflicts, and the
// barrier's vmcnt coupling to staging) cached data the L2 already caches
// (Common-mistake #7). B-fragments now load DIRECTLY from global/L2:
// per wave per tile 16x global_load_dwordx2, lanes (q,l15) read 8 B at
// xb[(Jbase + colb)*128 + kt*32 + q*8] -> 16x32B segments per instr.
// Loads kept per-ct (<=8 load VGPRs live) to hold VGPR <= 64
// (4 blocks/CU; >64 halves occupancy). LDS is now just csbuf (4 KB);
// ONE barrier per tile protects double-buffered csbuf only.
// Block (I,s): A-panel register-resident; d-tiles s==0: d=0..8 else
// 8s+1..8s+8. Tile (I,d), J=(I+d)%128; row-sums in regs; col-sums (mirror
// rows, d not in {0,64}) via csbuf[ti&1] -> deferred block-private stores
// to colpart[d-1] after the next barrier. d==0 diag masked in epilogue.
// 512 thr = 8 waves; wave w: rows h*32 (h=w>>1), cols chalf*64 (chalf=w&1).
__global__ __launch_bounds__(512, 4)
void gram_tri_k(const unsigned char* __restrict__ xb, float* __restrict__ rowpart,
                float* __restrict__ colpart) {
  __shared__ float csbuf[2][512];  // 2 x 2 KB (double-buffered)

  const int tid = threadIdx.x;
  const int w = tid >> 6, lane = tid & 63;
  const int l15 = lane & 15, q = lane >> 4;
  const int I = (int)(blockIdx.x >> 3), s = (int)(blockIdx.x & 7);
  const int rI = I * 128;
  const int h = w >> 1, chalf = w & 1;
  const int dstart = (s == 0) ? 0 : 8 * s + 1;
  const int ntiles = (s == 0) ? 9 : 8;

  // A frags: 16x16x32 fp8 A[m=l15][k = q*8 + j] -> 8 contiguous bytes/lane
  long af[2][4];
  const unsigned char* gA = xb + (size_t)(rI + h * 32 + l15) * DDIM + q * 8;
#pragma unroll
  for (int rt = 0; rt < 2; ++rt)
#pragma unroll
    for (int kt = 0; kt < 4; ++kt)
      af[rt][kt] = *(const long*)(gA + rt * 16 * DDIM + kt * 32);

  // per-lane B base offset within a J-panel: col = chalf*64 + l15 (+ct*16),
  // byte k = q*8 (+kt*32); panel base added per tile.
  const unsigned char* gBlane = xb + (size_t)(chalf * 64 + l15) * DDIM + q * 8;

  float rs[2][4];
#pragma unroll
  for (int rt = 0; rt < 2; ++rt)
#pragma unroll
    for (int r = 0; r < 4; ++r) rs[rt][r] = 0.f;

  for (int ti = 0; ti < ntiles; ++ti) {
    const int d = dstart + ti;
    __syncthreads();  // csbuf[(ti-1)&1] complete; csbuf[ti&1] readers done
    // deferred colpart store for tile ti-1 (block-private plain store)
    if (ti > 0) {
      const int pd = d - 1;
      if (pd != 0 && pd != 64 && tid < 128) {
        const float* cb = csbuf[(ti - 1) & 1];
        colpart[(size_t)(pd - 1) * NROWS + ((I + pd) & 127) * 128 + tid] =
            cb[tid] + cb[128 + tid] + cb[256 + tid] + cb[384 + tid];
      }
    }
    const unsigned char* gB = gBlane + (size_t)(((I + d) & 127) * 128) * DDIM;
    const bool dz = (d == 0);  // uniform; only s==0/ti==0 blocks pay the mask

    float cstile[4];
#pragma unroll
    for (int ct = 0; ct < 4; ++ct) {
      long bfr[4];
#pragma unroll
      for (int kt = 0; kt < 4; ++kt)
        bfr[kt] = *(const long*)(gB + ct * 16 * DDIM + kt * 32);
      const int colb = chalf * 64 + ct * 16 + l15;
      float csl = 0.f;
#pragma unroll
      for (int rt = 0; rt < 2; ++rt) {
        f32x4 a = {0.f, 0.f, 0.f, 0.f};
#pragma unroll
        for (int kt = 0; kt < 4; ++kt)
          a = __builtin_amdgcn_mfma_f32_16x16x32_fp8_fp8(af[rt][kt], bfr[kt], a, 0, 0, 0);
        // C/D layout (dtype-independent): col = l15, row = q*4 + r
#pragma unroll
        for (int r = 0; r < 4; ++r) {
          float e = __builtin_amdgcn_exp2f(a[r]);
          if (dz && (h * 32 + rt * 16 + q * 4 + r) == colb) e = 0.f;  // mask diag
          rs[rt][r] += e;
          csl += e;
        }
      }
      cstile[ct] = csl;
    }
    // col partial: reduce over q (wave's 32 rows), stash per-(h,chalf) in
    // THIS tile's csbuf buffer; consumed after the NEXT barrier.
#pragma unroll
    for (int m = 16; m <= 32; m <<= 1)
#pragma unroll
      for (int ct = 0; ct < 4; ++ct)
        cstile[ct] += __shfl_xor(cstile[ct], m, 64);
    if (q == 0) {
#pragma unroll
      for (int ct = 0; ct < 4; ++ct)
        csbuf[ti & 1][h * 128 + chalf * 64 + ct * 16 + l15] = cstile[ct];
    }
  }
  __syncthreads();  // csbuf[(ntiles-1)&1] complete
  // colpart store for the last tile
  {
    const int pd = dstart + ntiles - 1;
    if (pd != 0 && pd != 64 && tid < 128) {
      const float* cb = csbuf[(ntiles - 1) & 1];
      colpart[(size_t)(pd - 1) * NROWS + ((I + pd) & 127) * 128 + tid] =
          cb[tid] + cb[128 + tid] + cb[256 + tid] + cb[384 + tid];
    }
  }

  // rows: reduce over the 16 cols (l15) within each wave's 64-col half...
#pragma unroll
  for (int m = 1; m <= 8; m <<= 1)
#pragma unroll
    for (int rt = 0; rt < 2; ++rt)
#pragma unroll
      for (int r = 0; r < 4; ++r)
        rs[rt][r] += __shfl_xor(rs[rt][r], m, 64);
  // ...then combine chalf halves through csbuf[0]; chalf=0 is the unique writer.
  __syncthreads();  // last colpart store done reading csbuf
  if (chalf == 1 && l15 == 0) {
#pragma unroll
    for (int rt = 0; rt < 2; ++rt)
#pragma unroll
      for (int r = 0; r < 4; ++r)
        csbuf[0][h * 32 + rt * 16 + q * 4 + r] = rs[rt][r];
  }
  __syncthreads();
  if (chalf == 0 && l15 == 0) {
#pragma unroll
    for (int rt = 0; rt < 2; ++rt)
#pragma unroll
      for (int r = 0; r < 4; ++r) {
        const int ro = h * 32 + rt * 16 + q * 4 + r;
        rowpart[(size_t)s * NROWS + rI + ro] = rs[rt][r] + csbuf[0][ro];
      }
  }
}

// [Round-6: exact revert to the r2 float4 finalize — r5's one-row-per-thread
// scalar variant regressed ~+9 us/launch.] 64 blocks x 64 threads, 4 rows
// per thread via float4: sums 8 rowpart + 63 colpart slices, adds the
// analytic diagonal 2^S, logs, wave-reduces, grid-atomic finish.
__global__ void finalize_k(const float* __restrict__ rowpart, const float* __restrict__ colpart,
                           float* __restrict__ accum, int* __restrict__ cnt,
                           float* __restrict__ out) {
  const int tid = threadIdx.x;
  const size_t i4 = (size_t)(blockIdx.x * 64 + tid) * 4;
  const float DIAG = __builtin_exp2f(S_EXP);  // exact e^{1/T}, rows unit-norm
  float4 v = {DIAG, DIAG, DIAG, DIAG};
#pragma unroll
  for (int s2 = 0; s2 < 8; ++s2) {
    float4 t = *(const float4*)&rowpart[(size_t)s2 * NROWS + i4];
    v.x += t.x; v.y += t.y; v.z += t.z; v.w += t.w;
  }
#pragma unroll
  for (int d = 1; d < 64; ++d) {
    float4 t = *(const float4*)&colpart[(size_t)(d - 1) * NROWS + i4];
    v.x += t.x; v.y += t.y; v.z += t.z; v.w += t.w;
  }
  float sm = __logf(v.x) + __logf(v.y) + __logf(v.z) + __logf(v.w);
#pragma unroll
  for (int m = 1; m < 64; m <<= 1) sm += __shfl_xor(sm, m, 64);
  if (tid == 0) {
    atomicAdd(accum, sm);
    __threadfence();
    int prev = atomicAdd(cnt, 1);
    if (prev == (int)gridDim.x - 1) {
      __threadfence();
      float a = __hip_atomic_load(accum, __ATOMIC_RELAXED, __HIP_MEMORY_SCOPE_AGENT);
      out[0] = a / (float)NROWS;
    }
  }
}

extern "C" void kernel_launch(void* const* d_in, const int* in_sizes, int n_in,
                              void* d_out, int out_size, void* d_ws, size_t ws_size,
                              hipStream_t stream) {
  const float* x = (const float*)d_in[0];
  float* out = (float*)d_out;
  // ws layout: xb 2 MB (fp8) | rowpart 8x64KB | colpart 63x64KB | accum,cnt
  unsigned char* xb = (unsigned char*)d_ws;
  float* rowpart = (float*)((char*)d_ws + (size_t)NROWS * DDIM);
  float* colpart = rowpart + (size_t)8 * NROWS;
  float* accum = colpart + (size_t)63 * NROWS;
  int* cnt = (int*)(accum + 1);

  convert_k<<<NROWS * DDIM / (256 * 4), 256, 0, stream>>>(x, xb, accum, cnt);
  gram_tri_k<<<128 * 8, 512, 0, stream>>>(xb, rowpart, colpart);
  finalize_k<<<NROWS / 256, 64, 0, stream>>>(rowpart, colpart, accum, cnt, out);
}

// Round 7
// 112.400 us; speedup vs baseline: 1.8353x; 1.8353x over previous
//
#include <hip/hip_runtime.h>
#include <math.h>

// Problem constants (reference: N=16384, D=128, T=0.07)
#define NROWS 16384
#define DDIM  128
constexpr float TEMP = 0.07f;
// Pre-scale trick: x *= sqrt(log2(e)/T) so MFMA emits acc = S*<xi,xj> and
// row_lse = ln(sum exp2(acc)). The DIAGONAL (sim_ii = 1 exactly, rows unit
// norm) is masked out of the MFMA path and added analytically in finalize:
// rowsum_i = offdiag_fp8_sum_i + 2^S. Off-diag is only ~2.3% of rowsum, so
// fp8 e4m3 error there is damped ~44x -> absmax ~0.006 vs threshold 0.286.
constexpr float S_EXP = 1.44269504088896f / TEMP;  // 20.6099291

typedef __attribute__((ext_vector_type(4))) float f32x4;

// Convert + pre-scale to fp8 e4m3, writing a FRAGMENT-PACKED layout:
// byte addr = panel*16384 + ct_h*2048 + kt*512 + q*128 + l15*8 + b where
// row = panel*128 + ct_h*16 + l15, k = kt*32 + q*8 + b. A wave's MFMA
// fragment load (lane = q*16+l15, 8 B/lane) is then ONE contiguous 512 B
// global_load_dwordx2 -> 8 cache lines/instr, L1-shareable across waves.
// (Round-6 lesson: row-major L2-direct loads gathered 16 scattered lines
// per instr and were MSHR/transaction-bound, 3x regression.)
__global__ void convert_k(const float* __restrict__ x, unsigned char* __restrict__ xbp,
                          float* __restrict__ accum, int* __restrict__ cnt) {
  const float R = 4.53981419f;  // sqrt(S_EXP); |x*R| <= ~1.3, well inside e4m3 range
  const int gid = blockIdx.x * blockDim.x + threadIdx.x;
  const int i = gid * 4;
  float4 v = *(const float4*)(x + i);
  int p = __builtin_amdgcn_cvt_pk_fp8_f32(v.x * R, v.y * R, 0, false);
  p = __builtin_amdgcn_cvt_pk_fp8_f32(v.z * R, v.w * R, p, true);
  const int row = i >> 7, k0 = i & 127;
  const int panel = row >> 7, c7 = row & 127;
  const int cth = c7 >> 4, l15 = c7 & 15;
  const int kt = k0 >> 5, q = (k0 >> 3) & 3, b = k0 & 7;  // b in {0,4}
  *(int*)(xbp + ((size_t)panel << 14) + (cth << 11) + (kt << 9) + (q << 7) +
          (l15 << 3) + b) = p;
  if (gid == 0) { *accum = 0.f; *cnt = 0; }
}

// Triangular Gram in fp8 — ROUND-7: NO LDS for panels; A AND B fragments
// load directly from the packed layout (one contiguous 512 B dwordx2 per
// fragment, L2-resident 2 MB, 4-way wave sharing -> L1 hits). This deletes
// the staging apparatus entirely: no gload_lds, no panel LDS, no bank
// conflicts, no lgkm waits, no staging-vmcnt coupling at the barrier.
// LDS is only csbuf (4 KB); ONE barrier/tile protects double-buffered
// csbuf (r2-verified structure). Compute body identical to r6 (which
// PASSED correctness) — only load addresses changed.
// Block (I,s): d-tiles s==0: d=0..8 else 8s+1..8s+8. Tile (I,d),
// J=(I+d)%128; row-sums in regs; col-sums (mirror rows, d not in {0,64})
// via csbuf[ti&1] -> deferred block-private stores to colpart[d-1] after
// the next barrier. d==0 diag masked in epilogue (uniform-false elsewhere).
// 512 thr = 8 waves; wave w: rows h*32 (h=w>>1), cols chalf*64 (chalf=w&1).
__global__ __launch_bounds__(512, 4)
void gram_tri_k(const unsigned char* __restrict__ xbp, float* __restrict__ rowpart,
                float* __restrict__ colpart) {
  __shared__ float csbuf[2][512];  // 2 x 2 KB (double-buffered)

  const int tid = threadIdx.x;
  const int w = tid >> 6, lane = tid & 63;
  const int l15 = lane & 15, q = lane >> 4;
  const int I = (int)(blockIdx.x >> 3), s = (int)(blockIdx.x & 7);
  const int rI = I * 128;
  const int h = w >> 1, chalf = w & 1;
  const int dstart = (s == 0) ? 0 : 8 * s + 1;
  const int ntiles = (s == 0) ? 9 : 8;

  // A frags: rows h*32 + rt*16 + l15 -> packed ct_h = h*2 + rt; 8 B/lane
  long af[2][4];
  const unsigned char* gA = xbp + ((size_t)I << 14) + ((h * 2) << 11) + lane * 8;
#pragma unroll
  for (int rt = 0; rt < 2; ++rt)
#pragma unroll
    for (int kt = 0; kt < 4; ++kt)
      af[rt][kt] = *(const long*)(gA + (rt << 11) + (kt << 9));

  // B lane base: cols chalf*64 + ct*16 + l15 -> packed ct_h = chalf*4 + ct
  const unsigned char* gBlane = xbp + ((chalf * 4) << 11) + lane * 8;

  float rs[2][4];
#pragma unroll
  for (int rt = 0; rt < 2; ++rt)
#pragma unroll
    for (int r = 0; r < 4; ++r) rs[rt][r] = 0.f;

  for (int ti = 0; ti < ntiles; ++ti) {
    const int d = dstart + ti;
    __syncthreads();  // csbuf[(ti-1)&1] complete; csbuf[ti&1] readers done
    // deferred colpart store for tile ti-1 (block-private plain store)
    if (ti > 0) {
      const int pd = d - 1;
      if (pd != 0 && pd != 64 && tid < 128) {
        const float* cb = csbuf[(ti - 1) & 1];
        colpart[(size_t)(pd - 1) * NROWS + ((I + pd) & 127) * 128 + tid] =
            cb[tid] + cb[128 + tid] + cb[256 + tid] + cb[384 + tid];
      }
    }
    const unsigned char* gB = gBlane + ((size_t)((I + d) & 127) << 14);
    const bool dz = (d == 0);  // uniform; only s==0/ti==0 blocks pay the mask

    float cstile[4];
#pragma unroll
    for (int ct = 0; ct < 4; ++ct) {
      long bfr[4];
#pragma unroll
      for (int kt = 0; kt < 4; ++kt)
        bfr[kt] = *(const long*)(gB + (ct << 11) + (kt << 9));
      const int colb = chalf * 64 + ct * 16 + l15;
      float csl = 0.f;
#pragma unroll
      for (int rt = 0; rt < 2; ++rt) {
        f32x4 a = {0.f, 0.f, 0.f, 0.f};
#pragma unroll
        for (int kt = 0; kt < 4; ++kt)
          a = __builtin_amdgcn_mfma_f32_16x16x32_fp8_fp8(af[rt][kt], bfr[kt], a, 0, 0, 0);
        // C/D layout (dtype-independent): col = l15, row = q*4 + r
#pragma unroll
        for (int r = 0; r < 4; ++r) {
          float e = __builtin_amdgcn_exp2f(a[r]);
          if (dz && (h * 32 + rt * 16 + q * 4 + r) == colb) e = 0.f;  // mask diag
          rs[rt][r] += e;
          csl += e;
        }
      }
      cstile[ct] = csl;
    }
    // col partial: reduce over q (wave's 32 rows), stash per-(h,chalf) in
    // THIS tile's csbuf buffer; consumed after the NEXT barrier.
#pragma unroll
    for (int m = 16; m <= 32; m <<= 1)
#pragma unroll
      for (int ct = 0; ct < 4; ++ct)
        cstile[ct] += __shfl_xor(cstile[ct], m, 64);
    if (q == 0) {
#pragma unroll
      for (int ct = 0; ct < 4; ++ct)
        csbuf[ti & 1][h * 128 + chalf * 64 + ct * 16 + l15] = cstile[ct];
    }
  }
  __syncthreads();  // csbuf[(ntiles-1)&1] complete
  // colpart store for the last tile
  {
    const int pd = dstart + ntiles - 1;
    if (pd != 0 && pd != 64 && tid < 128) {
      const float* cb = csbuf[(ntiles - 1) & 1];
      colpart[(size_t)(pd - 1) * NROWS + ((I + pd) & 127) * 128 + tid] =
          cb[tid] + cb[128 + tid] + cb[256 + tid] + cb[384 + tid];
    }
  }

  // rows: reduce over the 16 cols (l15) within each wave's 64-col half...
#pragma unroll
  for (int m = 1; m <= 8; m <<= 1)
#pragma unroll
    for (int rt = 0; rt < 2; ++rt)
#pragma unroll
      for (int r = 0; r < 4; ++r)
        rs[rt][r] += __shfl_xor(rs[rt][r], m, 64);
  // ...then combine chalf halves through csbuf[0]; chalf=0 is the unique writer.
  __syncthreads();  // last colpart store done reading csbuf
  if (chalf == 1 && l15 == 0) {
#pragma unroll
    for (int rt = 0; rt < 2; ++rt)
#pragma unroll
      for (int r = 0; r < 4; ++r)
        csbuf[0][h * 32 + rt * 16 + q * 4 + r] = rs[rt][r];
  }
  __syncthreads();
  if (chalf == 0 && l15 == 0) {
#pragma unroll
    for (int rt = 0; rt < 2; ++rt)
#pragma unroll
      for (int r = 0; r < 4; ++r) {
        const int ro = h * 32 + rt * 16 + q * 4 + r;
        rowpart[(size_t)s * NROWS + rI + ro] = rs[rt][r] + csbuf[0][ro];
      }
  }
}

// 64 blocks x 64 threads, 4 rows/thread via float4 (r2-verified form):
// sums 8 rowpart + 63 colpart slices, adds the analytic diagonal 2^S,
// logs, wave-reduces, grid-atomic finish.
__global__ void finalize_k(const float* __restrict__ rowpart, const float* __restrict__ colpart,
                           float* __restrict__ accum, int* __restrict__ cnt,
                           float* __restrict__ out) {
  const int tid = threadIdx.x;
  const size_t i4 = (size_t)(blockIdx.x * 64 + tid) * 4;
  const float DIAG = __builtin_exp2f(S_EXP);  // exact e^{1/T}, rows unit-norm
  float4 v = {DIAG, DIAG, DIAG, DIAG};
#pragma unroll
  for (int s2 = 0; s2 < 8; ++s2) {
    float4 t = *(const float4*)&rowpart[(size_t)s2 * NROWS + i4];
    v.x += t.x; v.y += t.y; v.z += t.z; v.w += t.w;
  }
#pragma unroll
  for (int d = 1; d < 64; ++d) {
    float4 t = *(const float4*)&colpart[(size_t)(d - 1) * NROWS + i4];
    v.x += t.x; v.y += t.y; v.z += t.z; v.w += t.w;
  }
  float sm = __logf(v.x) + __logf(v.y) + __logf(v.z) + __logf(v.w);
#pragma unroll
  for (int m = 1; m < 64; m <<= 1) sm += __shfl_xor(sm, m, 64);
  if (tid == 0) {
    atomicAdd(accum, sm);
    __threadfence();
    int prev = atomicAdd(cnt, 1);
    if (prev == (int)gridDim.x - 1) {
      __threadfence();
      float a = __hip_atomic_load(accum, __ATOMIC_RELAXED, __HIP_MEMORY_SCOPE_AGENT);
      out[0] = a / (float)NROWS;
    }
  }
}

extern "C" void kernel_launch(void* const* d_in, const int* in_sizes, int n_in,
                              void* d_out, int out_size, void* d_ws, size_t ws_size,
                              hipStream_t stream) {
  const float* x = (const float*)d_in[0];
  float* out = (float*)d_out;
  // ws layout: xbp 2 MB (fp8, fragment-packed) | rowpart 8x64KB | colpart 63x64KB | accum,cnt
  unsigned char* xbp = (unsigned char*)d_ws;
  float* rowpart = (float*)((char*)d_ws + (size_t)NROWS * DDIM);
  float* colpart = rowpart + (size_t)8 * NROWS;
  float* accum = colpart + (size_t)63 * NROWS;
  int* cnt = (int*)(accum + 1);

  convert_k<<<NROWS * DDIM / (256 * 4), 256, 0, stream>>>(x, xbp, accum, cnt);
  gram_tri_k<<<128 * 8, 512, 0, stream>>>(xbp, rowpart, colpart);
  finalize_k<<<NROWS / 256, 64, 0, stream>>>(rowpart, colpart, accum, cnt, out);
}

// Round 8
// 104.896 us; speedup vs baseline: 1.9666x; 1.0715x over previous
//
#include <hip/hip_runtime.h>
#include <math.h>

// Problem constants (reference: N=16384, D=128, T=0.07)
#define NROWS 16384
#define DDIM  128
constexpr float TEMP = 0.07f;
// Pre-scale trick: x *= sqrt(log2(e)/T) so MFMA emits acc = S*<xi,xj> and
// row_lse = ln(sum exp2(acc)). The DIAGONAL (sim_ii = 1 exactly, rows unit
// norm) is masked out of the MFMA path and added analytically in finalize:
// rowsum_i = offdiag_fp8_sum_i + 2^S. Off-diag is only ~2.3% of rowsum, so
// fp8 e4m3 error there is damped ~44x -> absmax ~0.006 vs threshold 0.286.
constexpr float S_EXP = 1.44269504088896f / TEMP;  // 20.6099291

typedef __attribute__((ext_vector_type(4))) float f32x4;

// Convert + pre-scale to fp8 e4m3, writing a FRAGMENT-PACKED layout:
// byte addr = panel*16384 + ct_h*2048 + kt*512 + q*128 + l15*8 + b where
// row = panel*128 + ct_h*16 + l15, k = kt*32 + q*8 + b. A wave's MFMA
// fragment load (lane = q*16+l15, 8 B/lane) is then ONE contiguous 512 B
// global_load_dwordx2 -> 8 cache lines/instr, L1-shareable across waves.
// (Round-6 lesson: row-major L2-direct loads gathered 16 scattered lines
// per instr and were MSHR/transaction-bound, 3x regression.)
__global__ void convert_k(const float* __restrict__ x, unsigned char* __restrict__ xbp,
                          float* __restrict__ accum, int* __restrict__ cnt) {
  const float R = 4.53981419f;  // sqrt(S_EXP); |x*R| <= ~1.3, well inside e4m3 range
  const int gid = blockIdx.x * blockDim.x + threadIdx.x;
  const int i = gid * 4;
  float4 v = *(const float4*)(x + i);
  int p = __builtin_amdgcn_cvt_pk_fp8_f32(v.x * R, v.y * R, 0, false);
  p = __builtin_amdgcn_cvt_pk_fp8_f32(v.z * R, v.w * R, p, true);
  const int row = i >> 7, k0 = i & 127;
  const int panel = row >> 7, c7 = row & 127;
  const int cth = c7 >> 4, l15 = c7 & 15;
  const int kt = k0 >> 5, q = (k0 >> 3) & 3, b = k0 & 7;  // b in {0,4}
  *(int*)(xbp + ((size_t)panel << 14) + (cth << 11) + (kt << 9) + (q << 7) +
          (l15 << 3) + b) = p;
  if (gid == 0) { *accum = 0.f; *cnt = 0; }
}

// Triangular Gram in fp8 — ROUND-8: ZERO barriers in the tile loop.
// r0..r7 established: operand delivery is NOT the bottleneck (LDS-staged
// 51.5us, packed-L2-direct 54.4us, MfmaUtil ~25 both). The shared
// structural element was the per-tile __syncthreads (csbuf exchange),
// which phase-locks all 8 waves every tile, blocks cross-tile load
// pipelining (no global load may cross a barrier), and re-exposes L2
// latency per tile. Fix: per-tile per-wave PRIVATE col-sum slots
// csbuf[ti][h][col] (9x4x128 f32 = 18 KB, unique writer, never reused)
// -> the tile loop has NO synchronization at all. Col-sum h-reduction +
// colpart stores + row-sum chalf-exchange all happen in one epilogue
// behind a single barrier. Waves free-run and drift; compiler may
// pipeline tile ti+1 loads into tile ti compute.
// B/A fragments load directly from the packed layout (one contiguous
// 512 B dwordx2 per fragment, L2-resident 2 MB, 4-way wave sharing).
// Block (I,s): d-tiles s==0: d=0..8 else 8s+1..8s+8. Tile (I,d),
// J=(I+d)%128. d==0 diag masked in epilogue; d in {0,64} col-slices
// skipped at store time (mirror double-count).
// 512 thr = 8 waves; wave w: rows h*32 (h=w>>1), cols chalf*64 (chalf=w&1).
__global__ __launch_bounds__(512, 4)
void gram_tri_k(const unsigned char* __restrict__ xbp, float* __restrict__ rowpart,
                float* __restrict__ colpart) {
  __shared__ float csbuf[9][4][128];  // 18 KB: per-(tile,h) col partials
  __shared__ float rsx[128];          // row-sum chalf exchange (epilogue)

  const int tid = threadIdx.x;
  const int w = tid >> 6, lane = tid & 63;
  const int l15 = lane & 15, q = lane >> 4;
  const int I = (int)(blockIdx.x >> 3), s = (int)(blockIdx.x & 7);
  const int rI = I * 128;
  const int h = w >> 1, chalf = w & 1;
  const int dstart = (s == 0) ? 0 : 8 * s + 1;
  const int ntiles = (s == 0) ? 9 : 8;

  // A frags: rows h*32 + rt*16 + l15 -> packed ct_h = h*2 + rt; 8 B/lane
  long af[2][4];
  const unsigned char* gA = xbp + ((size_t)I << 14) + ((h * 2) << 11) + lane * 8;
#pragma unroll
  for (int rt = 0; rt < 2; ++rt)
#pragma unroll
    for (int kt = 0; kt < 4; ++kt)
      af[rt][kt] = *(const long*)(gA + (rt << 11) + (kt << 9));

  // B lane base: cols chalf*64 + ct*16 + l15 -> packed ct_h = chalf*4 + ct
  const unsigned char* gBlane = xbp + ((chalf * 4) << 11) + lane * 8;

  float rs[2][4];
#pragma unroll
  for (int rt = 0; rt < 2; ++rt)
#pragma unroll
    for (int r = 0; r < 4; ++r) rs[rt][r] = 0.f;

  for (int ti = 0; ti < ntiles; ++ti) {
    const int d = dstart + ti;
    const unsigned char* gB = gBlane + ((size_t)((I + d) & 127) << 14);
    const bool dz = (d == 0);  // uniform; only s==0/ti==0 blocks pay the mask

    float cstile[4];
#pragma unroll
    for (int ct = 0; ct < 4; ++ct) {
      long bfr[4];
#pragma unroll
      for (int kt = 0; kt < 4; ++kt)
        bfr[kt] = *(const long*)(gB + (ct << 11) + (kt << 9));
      const int colb = chalf * 64 + ct * 16 + l15;
      float csl = 0.f;
#pragma unroll
      for (int rt = 0; rt < 2; ++rt) {
        f32x4 a = {0.f, 0.f, 0.f, 0.f};
#pragma unroll
        for (int kt = 0; kt < 4; ++kt)
          a = __builtin_amdgcn_mfma_f32_16x16x32_fp8_fp8(af[rt][kt], bfr[kt], a, 0, 0, 0);
        // C/D layout (dtype-independent): col = l15, row = q*4 + r
#pragma unroll
        for (int r = 0; r < 4; ++r) {
          float e = __builtin_amdgcn_exp2f(a[r]);
          if (dz && (h * 32 + rt * 16 + q * 4 + r) == colb) e = 0.f;  // mask diag
          rs[rt][r] += e;
          csl += e;
        }
      }
      cstile[ct] = csl;
    }
    // col partial: reduce over q (wave's 32 rows), write this wave's
    // PRIVATE slot for this tile. No sync needed: unique writer, slot
    // never reused; consumed only after the epilogue barrier.
#pragma unroll
    for (int m = 16; m <= 32; m <<= 1)
#pragma unroll
      for (int ct = 0; ct < 4; ++ct)
        cstile[ct] += __shfl_xor(cstile[ct], m, 64);
    if (q == 0) {
#pragma unroll
      for (int ct = 0; ct < 4; ++ct)
        csbuf[ti][h][chalf * 64 + ct * 16 + l15] = cstile[ct];
    }
  }

  // rows: reduce over the 16 cols (l15) within each wave's 64-col half
  // (register-only; before the barrier so it overlaps other waves' tails)
#pragma unroll
  for (int m = 1; m <= 8; m <<= 1)
#pragma unroll
    for (int rt = 0; rt < 2; ++rt)
#pragma unroll
      for (int r = 0; r < 4; ++r)
        rs[rt][r] += __shfl_xor(rs[rt][r], m, 64);

  __syncthreads();  // THE ONLY barrier: all csbuf slots complete

  // colpart stores: (ti, col) entries, d not in {0,64}
  for (int e = tid; e < ntiles * 128; e += 512) {
    const int ti = e >> 7, col = e & 127;
    const int d = dstart + ti;
    if (d != 0 && d != 64)
      colpart[(size_t)(d - 1) * NROWS + ((I + d) & 127) * 128 + col] =
          csbuf[ti][0][col] + csbuf[ti][1][col] + csbuf[ti][2][col] + csbuf[ti][3][col];
  }
  // row-sum chalf exchange: chalf=1 publishes, chalf=0 combines+stores
  if (chalf == 1 && l15 == 0) {
#pragma unroll
    for (int rt = 0; rt < 2; ++rt)
#pragma unroll
      for (int r = 0; r < 4; ++r)
        rsx[h * 32 + rt * 16 + q * 4 + r] = rs[rt][r];
  }
  __syncthreads();
  if (chalf == 0 && l15 == 0) {
#pragma unroll
    for (int rt = 0; rt < 2; ++rt)
#pragma unroll
      for (int r = 0; r < 4; ++r) {
        const int ro = h * 32 + rt * 16 + q * 4 + r;
        rowpart[(size_t)s * NROWS + rI + ro] = rs[rt][r] + rsx[ro];
      }
  }
}

// 64 blocks x 64 threads, 4 rows/thread via float4 (r2-verified form):
// sums 8 rowpart + 63 colpart slices, adds the analytic diagonal 2^S,
// logs, wave-reduces, grid-atomic finish.
__global__ void finalize_k(const float* __restrict__ rowpart, const float* __restrict__ colpart,
                           float* __restrict__ accum, int* __restrict__ cnt,
                           float* __restrict__ out) {
  const int tid = threadIdx.x;
  const size_t i4 = (size_t)(blockIdx.x * 64 + tid) * 4;
  const float DIAG = __builtin_exp2f(S_EXP);  // exact e^{1/T}, rows unit-norm
  float4 v = {DIAG, DIAG, DIAG, DIAG};
#pragma unroll
  for (int s2 = 0; s2 < 8; ++s2) {
    float4 t = *(const float4*)&rowpart[(size_t)s2 * NROWS + i4];
    v.x += t.x; v.y += t.y; v.z += t.z; v.w += t.w;
  }
#pragma unroll
  for (int d = 1; d < 64; ++d) {
    float4 t = *(const float4*)&colpart[(size_t)(d - 1) * NROWS + i4];
    v.x += t.x; v.y += t.y; v.z += t.z; v.w += t.w;
  }
  float sm = __logf(v.x) + __logf(v.y) + __logf(v.z) + __logf(v.w);
#pragma unroll
  for (int m = 1; m < 64; m <<= 1) sm += __shfl_xor(sm, m, 64);
  if (tid == 0) {
    atomicAdd(accum, sm);
    __threadfence();
    int prev = atomicAdd(cnt, 1);
    if (prev == (int)gridDim.x - 1) {
      __threadfence();
      float a = __hip_atomic_load(accum, __ATOMIC_RELAXED, __HIP_MEMORY_SCOPE_AGENT);
      out[0] = a / (float)NROWS;
    }
  }
}

extern "C" void kernel_launch(void* const* d_in, const int* in_sizes, int n_in,
                              void* d_out, int out_size, void* d_ws, size_t ws_size,
                              hipStream_t stream) {
  const float* x = (const float*)d_in[0];
  float* out = (float*)d_out;
  // ws layout: xbp 2 MB (fp8, fragment-packed) | rowpart 8x64KB | colpart 63x64KB | accum,cnt
  unsigned char* xbp = (unsigned char*)d_ws;
  float* rowpart = (float*)((char*)d_ws + (size_t)NROWS * DDIM);
  float* colpart = rowpart + (size_t)8 * NROWS;
  float* accum = colpart + (size_t)63 * NROWS;
  int* cnt = (int*)(accum + 1);

  convert_k<<<NROWS * DDIM / (256 * 4), 256, 0, stream>>>(x, xbp, accum, cnt);
  gram_tri_k<<<128 * 8, 512, 0, stream>>>(xbp, rowpart, colpart);
  finalize_k<<<NROWS / 256, 64, 0, stream>>>(rowpart, colpart, accum, cnt, out);
}